// Round 4
// baseline (698.340 us; speedup 1.0000x reference)
//
#include <hip/hip_runtime.h>
#include <hip/hip_bf16.h>
#include <cfloat>

#define B_    1024
#define T_    4
#define DIN   768
#define KD    3072      // T_*DIN, contracted dim of encoder
#define DSAE  8192
#define TOPK  32
#define PK    40        // LDS row pitch in bf16 units (80 B)

static constexpr size_t XHAT_OFF = 1;
static constexpr size_t Z_OFF    = 1 + (size_t)B_ * T_ * DIN;   // 3145729 (4B-aligned only!)

typedef __attribute__((ext_vector_type(8))) short  frag;    // 8 bf16 = 4 VGPRs
typedef __attribute__((ext_vector_type(4))) float  f32x4;   // MFMA C/D

__device__ __forceinline__ unsigned pk_rn(float a, float b) {
    // round-to-nearest bf16 pair, packed (a low, b high) -> v_cvt_pk_bf16_f32
    __hip_bfloat162 h = __float22bfloat162_rn(float2{a, b});
    unsigned r;
    __builtin_memcpy(&r, &h, 4);    // bf162 isn't trivially copyable; memcpy = free bitcast
    return r;
}

// ---------------------------------------------------------------- K0
__global__ void zero_acc(double* acc) { if (threadIdx.x == 0) *acc = 0.0; }

// ---------------------------------------------------------------- K1: single-product bf16(rne) MFMA GEMM  pre = X*W + b_enc
// Membership correctness is restored later by margin-window + fp64 arbitration in select_topk.
__global__ __launch_bounds__(256) void encode_mfma(const float* __restrict__ x,
                                                   const float* __restrict__ W,
                                                   const float* __restrict__ benc,
                                                   float* __restrict__ pre)
{
    __shared__ short Ah[2][128 * PK];   // [m][k], chunk-XOR swizzled, 10 KB each buf
    __shared__ short Bh[2][128 * PK];   // [n][k] (transposed W tile), swizzled

    const int tid = threadIdx.x;
    // XCD-aware swizzle: XCD k owns n-blocks [8k,8k+8) -> W read once per XCD
    const int id  = blockIdx.x;
    const int nb  = (id & 7) * 8 + ((id >> 3) >> 3);
    const int mb  = (id >> 3) & 7;
    const int m0  = mb * 128, n0 = nb * 128;

    // A loader: thread -> (row am, 16 k at ak)
    const int am = tid >> 1, ak16 = (tid & 1);         // ak = ak16*16
    // B loader: thread -> 4k x 4n block
    const int kb4 = (tid >> 5) * 4, bn = (tid & 31) * 4;
    // lane/fragment ids
    const int l = tid & 63, wv = tid >> 6;
    const int half = (l >> 5) & 1;
    const int wrow = (wv >> 1) * 64, wcol = (wv & 1) * 64;
    const int lm = l & 15, q = l >> 4;
    const int sx = (lm >> 3) & 1;
    const int koff = ((q ^ sx) << 3);                  // swizzled k-offset (shorts)

    // precomputed LDS store offsets (shorts)
    const int sAsw = (am >> 3) & 1;
    const int sA0  = am * PK + (((ak16 * 2 + 0) ^ sAsw) << 3);
    const int sA1  = am * PK + (((ak16 * 2 + 1) ^ sAsw) << 3);
    const int nrow0 = bn + 2 * half;                   // even; nrow1 = nrow0+1 shares (n>>3)
    const int sBsw  = (nrow0 >> 3) & 1;
    const int sB0   = nrow0 * PK + ((wv ^ sBsw) << 3);
    const int sB1   = (nrow0 + 1) * PK + ((wv ^ sBsw) << 3);

    f32x4 acc[4][4];
    #pragma unroll
    for (int i = 0; i < 4; i++)
        #pragma unroll
        for (int j = 0; j < 4; j++) acc[i][j] = (f32x4){0.f, 0.f, 0.f, 0.f};

    const float* pA = x + (size_t)(m0 + am) * KD + ak16 * 16;
    const float* pB = W + (size_t)kb4 * DSAE + n0 + bn;

    float4 fa0, fa1, fa2, fa3, fb0, fb1, fb2, fb3;

    #define LOADS(K0)  do {                                               \
        const float* pa = pA + (K0);                                      \
        fa0 = *(const float4*)(pa);      fa1 = *(const float4*)(pa + 4);  \
        fa2 = *(const float4*)(pa + 8);  fa3 = *(const float4*)(pa + 12); \
        const float* pb = pB + (size_t)(K0) * DSAE;                       \
        fb0 = *(const float4*)(pb);                                       \
        fb1 = *(const float4*)(pb + DSAE);                                \
        fb2 = *(const float4*)(pb + 2 * DSAE);                            \
        fb3 = *(const float4*)(pb + 3 * DSAE);                            \
    } while (0)

    #define CVTSTORE(BUF) do {                                                         \
        unsigned ha[8];                                                                \
        ha[0] = pk_rn(fa0.x, fa0.y); ha[1] = pk_rn(fa0.z, fa0.w);                      \
        ha[2] = pk_rn(fa1.x, fa1.y); ha[3] = pk_rn(fa1.z, fa1.w);                      \
        ha[4] = pk_rn(fa2.x, fa2.y); ha[5] = pk_rn(fa2.z, fa2.w);                      \
        ha[6] = pk_rn(fa3.x, fa3.y); ha[7] = pk_rn(fa3.z, fa3.w);                      \
        *(int4*)&Ah[BUF][sA0] = make_int4(ha[0], ha[1], ha[2], ha[3]);                 \
        *(int4*)&Ah[BUF][sA1] = make_int4(ha[4], ha[5], ha[6], ha[7]);                 \
        unsigned p01[4], p23[4];                                                       \
        p01[0] = pk_rn(fb0.x, fb1.x); p23[0] = pk_rn(fb2.x, fb3.x);                    \
        p01[1] = pk_rn(fb0.y, fb1.y); p23[1] = pk_rn(fb2.y, fb3.y);                    \
        p01[2] = pk_rn(fb0.z, fb1.z); p23[2] = pk_rn(fb2.z, fb3.z);                    \
        p01[3] = pk_rn(fb0.w, fb1.w); p23[3] = pk_rn(fb2.w, fb3.w);                    \
        unsigned sx0 = half ? p01[0] : p01[2], sx1 = half ? p23[0] : p23[2];           \
        unsigned sy0 = half ? p01[1] : p01[3], sy1 = half ? p23[1] : p23[3];           \
        unsigned rx0 = (unsigned)__shfl_xor((int)sx0, 32);                             \
        unsigned rx1 = (unsigned)__shfl_xor((int)sx1, 32);                             \
        unsigned ry0 = (unsigned)__shfl_xor((int)sy0, 32);                             \
        unsigned ry1 = (unsigned)__shfl_xor((int)sy1, 32);                             \
        unsigned kx0 = half ? p01[2] : p01[0], kx1 = half ? p23[2] : p23[0];           \
        unsigned ky0 = half ? p01[3] : p01[1], ky1 = half ? p23[3] : p23[1];           \
        int4 w0 = half ? make_int4(rx0, rx1, kx0, kx1) : make_int4(kx0, kx1, rx0, rx1);\
        int4 w1 = half ? make_int4(ry0, ry1, ky0, ky1) : make_int4(ky0, ky1, ry0, ry1);\
        *(int4*)&Bh[BUF][sB0] = w0;                                                    \
        *(int4*)&Bh[BUF][sB1] = w1;                                                    \
    } while (0)

    #define COMPUTE(BUF) do {                                                          \
        frag av[4], bv[4];                                                             \
        _Pragma("unroll")                                                              \
        for (int t4 = 0; t4 < 4; t4++) {                                               \
            av[t4] = *(const frag*)&Ah[BUF][(wrow + t4 * 16 + lm) * PK + koff];        \
            bv[t4] = *(const frag*)&Bh[BUF][(wcol + t4 * 16 + lm) * PK + koff];        \
        }                                                                              \
        _Pragma("unroll")                                                              \
        for (int mt = 0; mt < 4; mt++)                                                 \
            _Pragma("unroll")                                                          \
            for (int nt = 0; nt < 4; nt++)                                             \
                acc[mt][nt] = __builtin_amdgcn_mfma_f32_16x16x32_bf16(av[mt], bv[nt],  \
                                                                      acc[mt][nt], 0, 0, 0); \
    } while (0)

    LOADS(0);
    CVTSTORE(0);
    __syncthreads();
    for (int ch = 0; ch < KD / 32; ch++) {
        if (ch + 1 < KD / 32) LOADS((ch + 1) * 32);
        COMPUTE(ch & 1);
        if (ch + 1 < KD / 32) CVTSTORE((ch + 1) & 1);
        __syncthreads();
    }

    // epilogue: C/D layout col=lane&15, row=q*4+reg
    #pragma unroll
    for (int mt = 0; mt < 4; mt++)
        #pragma unroll
        for (int nt = 0; nt < 4; nt++) {
            int col = n0 + wcol + nt * 16 + lm;
            float bvl = benc[col];
            #pragma unroll
            for (int r = 0; r < 4; r++) {
                int row = m0 + wrow + mt * 16 + q * 4 + r;
                pre[(size_t)row * DSAE + col] = acc[mt][nt][r] + bvl;
            }
        }
    #undef LOADS
    #undef CVTSTORE
    #undef COMPUTE
}

// ---------------------------------------------------------------- K2: exact top-32 selection (one block per row)
__global__ __launch_bounds__(256) void select_topk(float* __restrict__ zout,
                                                   const float* __restrict__ x,
                                                   const float* __restrict__ W,
                                                   int* __restrict__ widx_g,
                                                   float* __restrict__ wval_g)
{
    const int b   = blockIdx.x;
    const int tid = threadIdx.x;
    const int wv  = tid >> 6;

    __shared__ float vals[DSAE];            // 32 KB
    __shared__ unsigned char flag[DSAE];    // 8 KB
    __shared__ float wmax[4]; __shared__ int wmaxi[4];
    __shared__ double dred[256];
    __shared__ float topv[TOPK]; __shared__ int topi[TOPK];
    __shared__ int wix[64]; __shared__ double wdv[64]; __shared__ unsigned char wsel[64];
    __shared__ int wcnt, nabove, outc;

    float* zrow = zout + (size_t)b * DSAE;
    #pragma unroll
    for (int p = 0; p < DSAE / 256; p++) vals[tid + p * 256] = zrow[tid + p * 256];
    __syncthreads();

    // per-thread local argmax over strided stripe (i ≡ tid mod 256) — owner-unique
    float lv = -FLT_MAX; int li = tid;
    #pragma unroll
    for (int p = 0; p < DSAE / 256; p++) {
        int i = tid + p * 256; float v = vals[i];
        if (v > lv || (v == lv && i < li)) { lv = v; li = i; }
    }

    for (int pass = 0; pass < TOPK; pass++) {
        float v = lv; int idx = li;
        #pragma unroll
        for (int off = 32; off > 0; off >>= 1) {
            float ov = __shfl_down(v, off); int oi = __shfl_down(idx, off);
            if (ov > v || (ov == v && oi < idx)) { v = ov; idx = oi; }
        }
        if ((tid & 63) == 0) { wmax[wv] = v; wmaxi[wv] = idx; }
        __syncthreads();
        if (tid == 0) {
            float bv = wmax[0]; int bi = wmaxi[0];
            #pragma unroll
            for (int w = 1; w < 4; w++)
                if (wmax[w] > bv || (wmax[w] == bv && wmaxi[w] < bi)) { bv = wmax[w]; bi = wmaxi[w]; }
            topv[pass] = bv; topi[pass] = bi;
            vals[bi] = -FLT_MAX;
        }
        __syncthreads();
        if (li == topi[pass]) {                     // unique owner rescans its stripe
            lv = -FLT_MAX; li = tid;
            #pragma unroll
            for (int p = 0; p < DSAE / 256; p++) {
                int i = tid + p * 256; float v2 = vals[i];
                if (v2 > lv || (v2 == lv && i < li)) { lv = v2; li = i; }
            }
        }
    }
    if (tid < TOPK) vals[topi[tid]] = topv[tid];    // restore killed entries
    if (tid == 0) { wcnt = 0; nabove = 0; outc = 0; }
    __syncthreads();

    const float v32 = topv[TOPK - 1];
    const float mgn = 0.03f;   // 9.4 sigma of bf16-rne GEMM error (3.2e-3)

    for (int p = 0; p < DSAE / 256; p++) {
        int i = tid + p * 256;
        float v = vals[i];
        if (v > v32 + mgn) { atomicAdd(&nabove, 1); }
        else if (v >= v32 - mgn) { int slot = atomicAdd(&wcnt, 1); if (slot < 64) wix[slot] = i; }
    }
    __syncthreads();
    const int nw   = wcnt < 64 ? wcnt : 64;
    const int need = TOPK - nabove;

    if (nw == need) {
        if (tid < 64) wsel[tid] = (tid < nw) ? 1 : 0;
    } else {
        // fp64-exact re-computation of window atoms (~3 per row)
        const float* xr = x + (size_t)b * KD;
        for (int w = 0; w < nw; w++) {
            const int s = wix[w];
            double part = 0.0;
            for (int kk = tid; kk < KD; kk += 256)
                part += (double)xr[kk] * (double)W[(size_t)kk * DSAE + s];
            dred[tid] = part; __syncthreads();
            for (int st = 128; st > 0; st >>= 1) { if (tid < st) dred[tid] += dred[tid + st]; __syncthreads(); }
            if (tid == 0) wdv[w] = dred[0];
            __syncthreads();
        }
        if (tid < 64) {
            unsigned char sel = 0;
            if (tid < nw) {
                int rank = 0;
                double mv = wdv[tid]; int mi = wix[tid];
                for (int w2 = 0; w2 < nw; w2++)
                    if (wdv[w2] > mv || (wdv[w2] == mv && wix[w2] < mi)) rank++;
                sel = (rank < need) ? 1 : 0;
            }
            wsel[tid] = sel;
        }
    }
    __syncthreads();

    for (int p = 0; p < DSAE / 256; p++) flag[tid + p * 256] = 0;
    __syncthreads();
    for (int p = 0; p < DSAE / 256; p++) {
        int i = tid + p * 256;
        if (vals[i] > v32 + mgn) flag[i] = 1;
    }
    if (tid < nw && wsel[tid]) flag[wix[tid]] = 1;
    __syncthreads();

    for (int p = 0; p < DSAE / 256; p++) {
        int i = tid + p * 256;
        float v = vals[i];
        float zv = 0.f;
        if (flag[i]) {
            zv = v > 0.f ? v : 0.f;
            int slot = atomicAdd(&outc, 1);
            if (slot < TOPK) { widx_g[b * TOPK + slot] = i; wval_g[b * TOPK + slot] = zv; }
        }
        zrow[i] = zv;
    }
}

// ---------------------------------------------------------------- K3: sparse decode + fused loss (3 blocks per sample, float4 on Wdec)
__global__ __launch_bounds__(256) void decode_loss(const int* __restrict__ widx_g,
                                                   const float* __restrict__ wval_g,
                                                   const float* __restrict__ Wdec,
                                                   const float* __restrict__ bdec,
                                                   const float* __restrict__ x,
                                                   float* __restrict__ xhat,
                                                   double* __restrict__ acc)
{
    const int b = blockIdx.y, cb = blockIdx.x, tid = threadIdx.x;
    const int col4 = cb * 256 + tid;                 // float4 index within 3072-col row
    __shared__ int sidx[TOPK]; __shared__ float sval[TOPK];
    __shared__ double lred[4];
    if (tid < TOPK) { sidx[tid] = widx_g[b * TOPK + tid]; sval[tid] = wval_g[b * TOPK + tid]; }
    __syncthreads();

    float4 o = ((const float4*)bdec)[col4];
    #pragma unroll 4
    for (int j = 0; j < TOPK; j++) {
        float v = sval[j];
        float4 w = *(const float4*)(Wdec + (size_t)sidx[j] * KD + (size_t)col4 * 4);
        o.x = fmaf(v, w.x, o.x); o.y = fmaf(v, w.y, o.y);
        o.z = fmaf(v, w.z, o.z); o.w = fmaf(v, w.w, o.w);
    }

    float4 xv = ((const float4*)(x + (size_t)b * KD))[col4];
    float dx = o.x - xv.x, dy = o.y - xv.y, dz = o.z - xv.z, dw = o.w - xv.w;
    double ls = (double)dx * dx + (double)dy * dy + (double)dz * dz + (double)dw * dw;

    float* xo = xhat + (size_t)b * KD + (size_t)col4 * 4;   // 4B-aligned region: scalar stores
    xo[0] = o.x; xo[1] = o.y; xo[2] = o.z; xo[3] = o.w;

    #pragma unroll
    for (int off = 32; off > 0; off >>= 1) ls += __shfl_down(ls, off);
    if ((tid & 63) == 0) lred[tid >> 6] = ls;
    __syncthreads();
    if (tid == 0) atomicAdd(acc, lred[0] + lred[1] + lred[2] + lred[3]);
}

// ---------------------------------------------------------------- K4: finalize
__global__ void finalize(const double* __restrict__ acc, float* __restrict__ out)
{
    if (threadIdx.x == 0) out[0] = (float)(*acc / (double)(B_ * T_));
}

// ----------------------------------------------------------------
extern "C" void kernel_launch(void* const* d_in, const int* in_sizes, int n_in,
                              void* d_out, int out_size, void* d_ws, size_t ws_size,
                              hipStream_t stream)
{
    (void)in_sizes; (void)n_in; (void)out_size; (void)ws_size;
    const float* x    = (const float*)d_in[0];
    const float* Wenc = (const float*)d_in[1];
    const float* Wdec = (const float*)d_in[2];
    const float* benc = (const float*)d_in[3];
    const float* bdec = (const float*)d_in[4];

    float*  out    = (float*)d_out;
    double* acc    = (double*)d_ws;
    int*    widx_g = (int*)((char*)d_ws + 16);
    float*  wval_g = (float*)((char*)d_ws + 16 + (size_t)B_ * TOPK * 4);

    float* pre  = out + Z_OFF;     // z region doubles as the dense pre buffer
    float* xhat = out + XHAT_OFF;

    hipLaunchKernelGGL(zero_acc,    dim3(1),          dim3(1),   0, stream, acc);
    hipLaunchKernelGGL(encode_mfma, dim3(512),        dim3(256), 0, stream, x, Wenc, benc, pre);
    hipLaunchKernelGGL(select_topk, dim3(B_),         dim3(256), 0, stream, pre, x, Wenc, widx_g, wval_g);
    hipLaunchKernelGGL(decode_loss, dim3(3, B_),      dim3(256), 0, stream, widx_g, wval_g, Wdec, bdec, x, xhat, acc);
    hipLaunchKernelGGL(finalize,    dim3(1),          dim3(1),   0, stream, acc, out);
}